// Round 3
// baseline (1091.399 us; speedup 1.0000x reference)
//
#include <hip/hip_runtime.h>
#include <hip/hip_bf16.h>

// VectorQuantizer: z [8,64,64,64] fp32 (BCHW), embedding [8192,64] fp32.
// Outputs (concat): z_q [8,64,64,64] fp32 (BCHW), indices [32768] as fp32.
//
// argmin_n ||zn - e_n||^2 == argmin_n ( 0.5*se[n] - dot(zn, e_n) )
// (||zn||^2 const per pixel; x0.5 scaling exact in fp32 -> same ordering)

#define NPIX 32768
#define NE   8192
#define EDIM 64
#define HW   4096          // 64*64
#define NGRP 8
#define CPG  (NE / NGRP)   // 1024 codes per group
#define TILE 32            // codes staged in LDS per iteration
#define NT   (CPG / TILE)  // 32 tiles per group

// ---------------- K0: init packed argmin keys --------------------------------
__global__ __launch_bounds__(256) void k_init(unsigned long long* __restrict__ packed) {
    packed[blockIdx.x * 256 + threadIdx.x] = ~0ull;
}

// ---------------- K1: normalize codebook, store se_half = 0.5*sum(e_n^2) -----
__global__ __launch_bounds__(256) void k_norm_emb(const float* __restrict__ emb,
                                                  float* __restrict__ e_norm,
                                                  float* __restrict__ se_half) {
    const int wave = threadIdx.x >> 6;        // 4 waves/block, 1 code per wave
    const int lane = threadIdx.x & 63;
    const int n = blockIdx.x * 4 + wave;      // 0..8191
    float v = emb[n * EDIM + lane];
    float ss = v * v;
    #pragma unroll
    for (int off = 32; off; off >>= 1) ss += __shfl_xor(ss, off, 64);
    const float inv = 1.0f / fmaxf(sqrtf(ss), 1e-12f);
    const float en = v * inv;
    e_norm[n * EDIM + lane] = en;
    float s2 = en * en;
    #pragma unroll
    for (int off = 32; off; off >>= 1) s2 += __shfl_xor(s2, off, 64);
    if (lane == 0) se_half[n] = 0.5f * s2;
}

// map float to unsigned with same total order
__device__ __forceinline__ unsigned int order_u32(float f) {
    unsigned int s = __float_as_uint(f);
    return (s & 0x80000000u) ? ~s : (s | 0x80000000u);
}

// ---------------- K2: per-pixel partial argmin over one code group -----------
// launch_bounds(256,1): occupancy target 1 wave/EU -> register budget 512.
// zr[64] MUST stay in VGPRs; R1/R2 allocator capped at 56/52 regs and spilled
// it (scratch re-reads ~4.3 TB == the entire 650 us runtime).
// e-tile comes from LDS with wave-uniform addresses -> broadcast, no conflicts,
// no dependence on global-load scalarization.
__global__ __launch_bounds__(256, 1) void k_vq_partial(const float* __restrict__ z,
                                                       const float* __restrict__ e_norm,
                                                       const float* __restrict__ se_half,
                                                       unsigned long long* __restrict__ packed) {
    __shared__ float es[TILE * EDIM];   // 8 KB code tile
    __shared__ float ses[TILE];         // 0.5*||e||^2 for the tile

    const int p = blockIdx.x * 256 + threadIdx.x;   // pixel 0..32767
    const int g = blockIdx.y;                       // code group 0..7
    const int b  = p >> 12;                         // p / 4096
    const int hw = p & (HW - 1);

    // Load this pixel's channel vector (coalesced across lanes for each c),
    // L2-normalize into 16 float4 registers.
    const float* zp = z + b * (EDIM * HW) + hw;
    float4 zr[16];
    float ss = 0.0f;
    #pragma unroll
    for (int c4 = 0; c4 < 16; ++c4) {
        float4 v;
        v.x = zp[(4 * c4 + 0) * HW];
        v.y = zp[(4 * c4 + 1) * HW];
        v.z = zp[(4 * c4 + 2) * HW];
        v.w = zp[(4 * c4 + 3) * HW];
        ss = fmaf(v.x, v.x, ss); ss = fmaf(v.y, v.y, ss);
        ss = fmaf(v.z, v.z, ss); ss = fmaf(v.w, v.w, ss);
        zr[c4] = v;
    }
    const float inv = 1.0f / fmaxf(sqrtf(ss), 1e-12f);
    #pragma unroll
    for (int c4 = 0; c4 < 16; ++c4) {
        zr[c4].x *= inv; zr[c4].y *= inv; zr[c4].z *= inv; zr[c4].w *= inv;
    }

    float best = 3.0e38f;
    int bidx = 0;
    const int n0g = g * CPG;

    for (int t = 0; t < NT; ++t) {
        const int n0 = n0g + t * TILE;
        // ---- stage code tile into LDS (coalesced float4 loads) ----
        {
            const float4* src = (const float4*)(e_norm + n0 * EDIM);
            float4* dst = (float4*)es;
            #pragma unroll
            for (int k = 0; k < (TILE * EDIM / 4) / 256; ++k)   // 2 iters
                dst[k * 256 + threadIdx.x] = src[k * 256 + threadIdx.x];
            if (threadIdx.x < TILE / 4)
                ((float4*)ses)[threadIdx.x] = ((const float4*)(se_half + n0))[threadIdx.x];
        }
        __syncthreads();

        // ---- sweep the tile: wave-uniform LDS reads (broadcast) ----
        #pragma unroll 2
        for (int j = 0; j < TILE; ++j) {
            const float4* ej = (const float4*)(es + j * EDIM);
            float a0 = 0.0f, a1 = 0.0f, a2 = 0.0f, a3 = 0.0f;
            #pragma unroll
            for (int q = 0; q < 4; ++q) {
                const float4 e0 = ej[q * 4 + 0];
                const float4 e1 = ej[q * 4 + 1];
                const float4 e2 = ej[q * 4 + 2];
                const float4 e3 = ej[q * 4 + 3];
                const float4 z0 = zr[q * 4 + 0];
                const float4 z1 = zr[q * 4 + 1];
                const float4 z2 = zr[q * 4 + 2];
                const float4 z3 = zr[q * 4 + 3];
                a0 = fmaf(z0.x, e0.x, a0); a0 = fmaf(z0.y, e0.y, a0);
                a0 = fmaf(z0.z, e0.z, a0); a0 = fmaf(z0.w, e0.w, a0);
                a1 = fmaf(z1.x, e1.x, a1); a1 = fmaf(z1.y, e1.y, a1);
                a1 = fmaf(z1.z, e1.z, a1); a1 = fmaf(z1.w, e1.w, a1);
                a2 = fmaf(z2.x, e2.x, a2); a2 = fmaf(z2.y, e2.y, a2);
                a2 = fmaf(z2.z, e2.z, a2); a2 = fmaf(z2.w, e2.w, a2);
                a3 = fmaf(z3.x, e3.x, a3); a3 = fmaf(z3.y, e3.y, a3);
                a3 = fmaf(z3.z, e3.z, a3); a3 = fmaf(z3.w, e3.w, a3);
            }
            const float dot = (a0 + a1) + (a2 + a3);
            const float dist = ses[j] - dot;
            // strict < with ascending n keeps the smallest index on exact ties
            if (dist < best) { best = dist; bidx = n0 + j; }
        }
        __syncthreads();
    }

    // key = (order(dist) << 32) | idx ; u64 min == (min dist, tie -> min idx).
    const unsigned long long key =
        ((unsigned long long)order_u32(best) << 32) | (unsigned int)bidx;
    atomicMin(&packed[p], key);
}

// ---------------- K3: unpack winner, gather code, write outputs --------------
__global__ __launch_bounds__(256) void k_finalize(const unsigned long long* __restrict__ packed,
                                                  const float* __restrict__ e_norm,
                                                  float* __restrict__ out) {
    const int p = blockIdx.x * 256 + threadIdx.x;
    const int bidx = (int)(packed[p] & 0xFFFFFFFFull);
    out[NPIX * EDIM + p] = (float)bidx;   // indices block, as float values

    const int b  = p >> 12;
    const int hw = p & (HW - 1);
    float* op = out + b * (EDIM * HW) + hw;
    const float* ep = e_norm + bidx * EDIM;
    #pragma unroll
    for (int c = 0; c < EDIM; ++c) op[c * HW] = ep[c];   // coalesced per c
}

extern "C" void kernel_launch(void* const* d_in, const int* in_sizes, int n_in,
                              void* d_out, int out_size, void* d_ws, size_t ws_size,
                              hipStream_t stream) {
    const float* z   = (const float*)d_in[0];   // 2,097,152 fp32
    const float* emb = (const float*)d_in[1];   // 524,288 fp32
    float* out = (float*)d_out;                 // 2,129,920 fp32

    // workspace layout
    float* e_norm  = (float*)d_ws;                                // 524,288 fp32 (2 MB)
    float* se_half = e_norm + NE * EDIM;                          // 8,192 fp32
    unsigned long long* packed = (unsigned long long*)(se_half + NE); // 32,768 u64

    k_init<<<NPIX / 256, 256, 0, stream>>>(packed);
    k_norm_emb<<<NE / 4, 256, 0, stream>>>(emb, e_norm, se_half);
    k_vq_partial<<<dim3(NPIX / 256, NGRP), 256, 0, stream>>>(z, e_norm, se_half, packed);
    k_finalize<<<NPIX / 256, 256, 0, stream>>>(packed, e_norm, out);
}

// Round 4
// 774.443 us; speedup vs baseline: 1.4093x; 1.4093x over previous
//
#include <hip/hip_runtime.h>
#include <hip/hip_bf16.h>

// VectorQuantizer: z [8,64,64,64] fp32 (BCHW), embedding [8192,64] fp32.
// Outputs (concat): z_q [8,64,64,64] fp32 (BCHW), indices [32768] as fp32.
//
// argmin_n ||zn - e_n||^2 == argmin_n ( 0.5*se[n] - dot(zn, e_n) )
// (||zn||^2 const per pixel; x0.5 scaling exact in fp32 -> same ordering)
//
// R4 design notes (counter evidence):
//  - e reads from GLOBAL with wave-uniform address: R1/R2 SGPR_Count=96 proves
//    these scalarize to s_load (SGPR-resident e, free SMEM pipe). R3's LDS path
//    was ds_read-throughput-bound (16 x b128 x 12cyc = 192 cyc/code > 128 cyc FMA).
//  - __launch_bounds__(256,1): R3 proved this yields ~80 VGPRs and keeps zr[64]
//    in registers. R1/R2's default/(256,4) capped at 52-56 VGPRs and spilled zr
//    (scratch re-reads dominated: 654 us at VALUBusy 44%).

#define NPIX 32768
#define NE   8192
#define EDIM 64
#define HW   4096          // 64*64
#define NGRP 16
#define CPG  (NE / NGRP)   // 512 codes per group

// ---------------- K0: init packed argmin keys --------------------------------
__global__ __launch_bounds__(256) void k_init(unsigned long long* __restrict__ packed) {
    packed[blockIdx.x * 256 + threadIdx.x] = ~0ull;
}

// ---------------- K1: normalize codebook, store se_half = 0.5*sum(e_n^2) -----
__global__ __launch_bounds__(256) void k_norm_emb(const float* __restrict__ emb,
                                                  float* __restrict__ e_norm,
                                                  float* __restrict__ se_half) {
    const int wave = threadIdx.x >> 6;        // 4 waves/block, 1 code per wave
    const int lane = threadIdx.x & 63;
    const int n = blockIdx.x * 4 + wave;      // 0..8191
    float v = emb[n * EDIM + lane];
    float ss = v * v;
    #pragma unroll
    for (int off = 32; off; off >>= 1) ss += __shfl_xor(ss, off, 64);
    const float inv = 1.0f / fmaxf(sqrtf(ss), 1e-12f);
    const float en = v * inv;
    e_norm[n * EDIM + lane] = en;
    float s2 = en * en;
    #pragma unroll
    for (int off = 32; off; off >>= 1) s2 += __shfl_xor(s2, off, 64);
    if (lane == 0) se_half[n] = 0.5f * s2;
}

// map float to unsigned with same total order
__device__ __forceinline__ unsigned int order_u32(float f) {
    unsigned int s = __float_as_uint(f);
    return (s & 0x80000000u) ? ~s : (s | 0x80000000u);
}

// ---------------- K2: per-pixel partial argmin over one code group -----------
__global__ __launch_bounds__(256, 1) void k_vq_partial(const float* __restrict__ z,
                                                       const float* __restrict__ e_norm,
                                                       const float* __restrict__ se_half,
                                                       unsigned long long* __restrict__ packed) {
    const int p = blockIdx.x * 256 + threadIdx.x;   // pixel 0..32767
    const int g = blockIdx.y;                       // code group 0..15
    const int b  = p >> 12;                         // p / 4096
    const int hw = p & (HW - 1);

    // Load this pixel's channel vector (coalesced across lanes for each c),
    // L2-normalize into 16 float4 registers (64 VGPRs, must NOT spill).
    const float* zp = z + b * (EDIM * HW) + hw;
    float4 zr[16];
    float ss = 0.0f;
    #pragma unroll
    for (int c4 = 0; c4 < 16; ++c4) {
        float4 v;
        v.x = zp[(4 * c4 + 0) * HW];
        v.y = zp[(4 * c4 + 1) * HW];
        v.z = zp[(4 * c4 + 2) * HW];
        v.w = zp[(4 * c4 + 3) * HW];
        ss = fmaf(v.x, v.x, ss); ss = fmaf(v.y, v.y, ss);
        ss = fmaf(v.z, v.z, ss); ss = fmaf(v.w, v.w, ss);
        zr[c4] = v;
    }
    const float inv = 1.0f / fmaxf(sqrtf(ss), 1e-12f);
    #pragma unroll
    for (int c4 = 0; c4 < 16; ++c4) {
        zr[c4].x *= inv; zr[c4].y *= inv; zr[c4].z *= inv; zr[c4].w *= inv;
    }

    // Stream this group's codes; n is wave-uniform -> compiler emits s_load
    // (e values live in SGPRs; v_fma takes 1 SGPR operand).
    const float4* __restrict__ e4 = (const float4*)e_norm;
    float best = 3.0e38f;
    int bidx = 0;
    const int n0 = g * CPG;
    #pragma unroll 2
    for (int n = n0; n < n0 + CPG; ++n) {
        float a0 = 0.0f, a1 = 0.0f, a2 = 0.0f, a3 = 0.0f;
        #pragma unroll
        for (int q = 0; q < 4; ++q) {
            const float4 e0 = e4[n * (EDIM / 4) + q * 4 + 0];
            const float4 e1 = e4[n * (EDIM / 4) + q * 4 + 1];
            const float4 e2 = e4[n * (EDIM / 4) + q * 4 + 2];
            const float4 e3 = e4[n * (EDIM / 4) + q * 4 + 3];
            const float4 z0 = zr[q * 4 + 0];
            const float4 z1 = zr[q * 4 + 1];
            const float4 z2 = zr[q * 4 + 2];
            const float4 z3 = zr[q * 4 + 3];
            a0 = fmaf(z0.x, e0.x, a0); a0 = fmaf(z0.y, e0.y, a0);
            a0 = fmaf(z0.z, e0.z, a0); a0 = fmaf(z0.w, e0.w, a0);
            a1 = fmaf(z1.x, e1.x, a1); a1 = fmaf(z1.y, e1.y, a1);
            a1 = fmaf(z1.z, e1.z, a1); a1 = fmaf(z1.w, e1.w, a1);
            a2 = fmaf(z2.x, e2.x, a2); a2 = fmaf(z2.y, e2.y, a2);
            a2 = fmaf(z2.z, e2.z, a2); a2 = fmaf(z2.w, e2.w, a2);
            a3 = fmaf(z3.x, e3.x, a3); a3 = fmaf(z3.y, e3.y, a3);
            a3 = fmaf(z3.z, e3.z, a3); a3 = fmaf(z3.w, e3.w, a3);
        }
        const float dot = (a0 + a1) + (a2 + a3);
        const float dist = se_half[n] - dot;
        // strict < with ascending n keeps the smallest index on exact ties
        if (dist < best) { best = dist; bidx = n; }
    }
    // key = (order(dist) << 32) | idx ; u64 min == (min dist, tie -> min idx).
    const unsigned long long key =
        ((unsigned long long)order_u32(best) << 32) | (unsigned int)bidx;
    atomicMin(&packed[p], key);
}

// ---------------- K3: unpack winner, gather code, write outputs --------------
__global__ __launch_bounds__(256) void k_finalize(const unsigned long long* __restrict__ packed,
                                                  const float* __restrict__ e_norm,
                                                  float* __restrict__ out) {
    const int p = blockIdx.x * 256 + threadIdx.x;
    const int bidx = (int)(packed[p] & 0xFFFFFFFFull);
    out[NPIX * EDIM + p] = (float)bidx;   // indices block, as float values

    const int b  = p >> 12;
    const int hw = p & (HW - 1);
    float* op = out + b * (EDIM * HW) + hw;
    const float* ep = e_norm + bidx * EDIM;
    #pragma unroll
    for (int c = 0; c < EDIM; ++c) op[c * HW] = ep[c];   // coalesced per c
}

extern "C" void kernel_launch(void* const* d_in, const int* in_sizes, int n_in,
                              void* d_out, int out_size, void* d_ws, size_t ws_size,
                              hipStream_t stream) {
    const float* z   = (const float*)d_in[0];   // 2,097,152 fp32
    const float* emb = (const float*)d_in[1];   // 524,288 fp32
    float* out = (float*)d_out;                 // 2,129,920 fp32

    // workspace layout
    float* e_norm  = (float*)d_ws;                                // 524,288 fp32 (2 MB)
    float* se_half = e_norm + NE * EDIM;                          // 8,192 fp32
    unsigned long long* packed = (unsigned long long*)(se_half + NE); // 32,768 u64

    k_init<<<NPIX / 256, 256, 0, stream>>>(packed);
    k_norm_emb<<<NE / 4, 256, 0, stream>>>(emb, e_norm, se_half);
    k_vq_partial<<<dim3(NPIX / 256, NGRP), 256, 0, stream>>>(z, e_norm, se_half, packed);
    k_finalize<<<NPIX / 256, 256, 0, stream>>>(packed, e_norm, out);
}